// Round 1
// baseline (138.189 us; speedup 1.0000x reference)
//
#include <hip/hip_runtime.h>
#include <stdint.h>

#define NR 8192
#define DIM 512
#define BM 128
#define BN 128
#define BK 64

typedef __attribute__((ext_vector_type(8))) __bf16 bf16x8;
typedef __attribute__((ext_vector_type(4))) float f32x4;

static __device__ __forceinline__ unsigned short f2bf(float f) {
    union { float f; uint32_t u; } v; v.f = f;
    uint32_t u = v.u;
    u += 0x7FFFu + ((u >> 16) & 1u);   // RNE
    return (unsigned short)(u >> 16);
}

static __device__ __forceinline__ void gload_lds16(const void* g, void* l) {
    __builtin_amdgcn_global_load_lds(
        (__attribute__((address_space(1))) void*)(void*)g,
        (__attribute__((address_space(3))) void*)l,
        16, 0, 0);
}

// One block per row: norms (stored as reciprocals), exact fp32 diag term,
// fp32 -> bf16 conversion, and zero rowsum for this call.
__global__ void prep_kernel(const float* __restrict__ xi, const float* __restrict__ xj,
                            unsigned short* __restrict__ xib, unsigned short* __restrict__ xjb,
                            float* __restrict__ inv_ni, float* __restrict__ inv_nj,
                            float* __restrict__ diag, float* __restrict__ rowsum) {
    const int row = blockIdx.x;
    const int t = threadIdx.x;                 // 128 threads, 4 elems each
    const float4 a = ((const float4*)(xi + (size_t)row * DIM))[t];
    const float4 b = ((const float4*)(xj + (size_t)row * DIM))[t];

    float ssi = a.x*a.x + a.y*a.y + a.z*a.z + a.w*a.w;
    float ssj = b.x*b.x + b.y*b.y + b.z*b.z + b.w*b.w;
    float dot = a.x*b.x + a.y*b.y + a.z*b.z + a.w*b.w;

    ushort4 av = { f2bf(a.x), f2bf(a.y), f2bf(a.z), f2bf(a.w) };
    ushort4 bv = { f2bf(b.x), f2bf(b.y), f2bf(b.z), f2bf(b.w) };
    ((ushort4*)(xib + (size_t)row * DIM))[t] = av;
    ((ushort4*)(xjb + (size_t)row * DIM))[t] = bv;

    #pragma unroll
    for (int m = 32; m >= 1; m >>= 1) {
        ssi += __shfl_xor(ssi, m, 64);
        ssj += __shfl_xor(ssj, m, 64);
        dot += __shfl_xor(dot, m, 64);
    }
    __shared__ float red[6];
    const int wave = t >> 6, lane = t & 63;
    if (lane == 0) { red[wave*3+0] = ssi; red[wave*3+1] = ssj; red[wave*3+2] = dot; }
    __syncthreads();
    if (t == 0) {
        float si = red[0] + red[3];
        float sj = red[1] + red[4];
        float d  = red[2] + red[5];
        float ini = rsqrtf(fmaxf(si, 1e-30f));
        float inj = rsqrtf(fmaxf(sj, 1e-30f));
        inv_ni[row] = ini;
        inv_nj[row] = inj;
        diag[row] = d * ini * inj;   // exact-fp32 matched-pair cosine
        rowsum[row] = 0.0f;
    }
}

// Fused NT-GEMM + exp + row-sum. 128x128 tile, BK=64, 4 waves (2x2 of 64x64).
__global__ void gemm_rowsum(const unsigned short* __restrict__ A,
                            const unsigned short* __restrict__ B,
                            const float* __restrict__ inv_ni,
                            const float* __restrict__ inv_nj,
                            float* __restrict__ rowsum) {
    __shared__ unsigned short As[BM * BK];
    __shared__ unsigned short Bs[BN * BK];
    const int tid  = threadIdx.x;
    const int row0 = blockIdx.y * BM;
    const int col0 = blockIdx.x * BN;
    const int wid  = tid >> 6;
    const int lane = tid & 63;
    const int wm = wid >> 1, wn = wid & 1;
    const int lr = lane & 15, lk = lane >> 4;
    const int r_l = tid >> 3;   // staging row within 32-row chunk
    const int c8  = tid & 7;    // staging 16B slot within 128B row

    f32x4 acc[4][4] = {};

    for (int k0 = 0; k0 < DIM; k0 += BK) {
        __syncthreads();
        #pragma unroll
        for (int i = 0; i < 4; ++i) {
            const int r = i * 32 + r_l;
            gload_lds16(A + (size_t)(row0 + r) * DIM + k0 + c8 * 8,
                        As + r * BK + c8 * 8);
            gload_lds16(B + (size_t)(col0 + r) * DIM + k0 + c8 * 8,
                        Bs + r * BK + c8 * 8);
        }
        __syncthreads();
        #pragma unroll
        for (int kk = 0; kk < BK; kk += 32) {
            bf16x8 af[4], bg[4];
            #pragma unroll
            for (int m = 0; m < 4; ++m)
                af[m] = *(const bf16x8*)(As + (wm*64 + m*16 + lr) * BK + kk + lk*8);
            #pragma unroll
            for (int n = 0; n < 4; ++n)
                bg[n] = *(const bf16x8*)(Bs + (wn*64 + n*16 + lr) * BK + kk + lk*8);
            #pragma unroll
            for (int m = 0; m < 4; ++m) {
                #pragma unroll
                for (int n = 0; n < 4; ++n)
                    acc[m][n] = __builtin_amdgcn_mfma_f32_16x16x32_bf16(
                        af[m], bg[n], acc[m][n], 0, 0, 0);
            }
        }
    }

    // Epilogue: scale to cosine, exp, row-reduce (cols live in lanes lr=0..15),
    // one atomicAdd per row per wave.
    float inj[4];
    #pragma unroll
    for (int n = 0; n < 4; ++n)
        inj[n] = inv_nj[col0 + wn*64 + n*16 + lr];
    float ini[4][4];
    #pragma unroll
    for (int m = 0; m < 4; ++m)
        #pragma unroll
        for (int e = 0; e < 4; ++e)
            ini[m][e] = inv_ni[row0 + wm*64 + m*16 + lk*4 + e];

    #pragma unroll
    for (int m = 0; m < 4; ++m) {
        #pragma unroll
        for (int e = 0; e < 4; ++e) {
            float s = 0.0f;
            const float in_i = ini[m][e];
            #pragma unroll
            for (int n = 0; n < 4; ++n)
                s += __expf(acc[m][n][e] * in_i * inj[n]);
            s += __shfl_xor(s, 1, 64);
            s += __shfl_xor(s, 2, 64);
            s += __shfl_xor(s, 4, 64);
            s += __shfl_xor(s, 8, 64);
            if (lr == 0)
                atomicAdd(&rowsum[row0 + wm*64 + m*16 + lk*4 + e], s);
        }
    }
}

__global__ void finalize(const float* __restrict__ rowsum,
                         const float* __restrict__ diag,
                         float* __restrict__ out) {
    const float E1 = 2.7182818284590452f;  // exp(1/TAU)
    float acc = 0.0f;
    for (int i = threadIdx.x; i < NR; i += 256)
        acc += __logf(rowsum[i] - E1) - diag[i];
    #pragma unroll
    for (int m = 32; m >= 1; m >>= 1)
        acc += __shfl_xor(acc, m, 64);
    __shared__ float red[4];
    const int wave = threadIdx.x >> 6, lane = threadIdx.x & 63;
    if (lane == 0) red[wave] = acc;
    __syncthreads();
    if (threadIdx.x == 0)
        out[0] = (red[0] + red[1] + red[2] + red[3]) * (1.0f / NR);
}

extern "C" void kernel_launch(void* const* d_in, const int* in_sizes, int n_in,
                              void* d_out, int out_size, void* d_ws, size_t ws_size,
                              hipStream_t stream) {
    const float* xi = (const float*)d_in[0];
    const float* xj = (const float*)d_in[1];

    char* ws = (char*)d_ws;
    unsigned short* xib = (unsigned short*)ws;              // 8 MB
    unsigned short* xjb = xib + (size_t)NR * DIM;           // 8 MB
    float* inv_ni = (float*)(xjb + (size_t)NR * DIM);       // 32 KB
    float* inv_nj = inv_ni + NR;
    float* diag   = inv_nj + NR;
    float* rowsum = diag + NR;

    prep_kernel<<<NR, 128, 0, stream>>>(xi, xj, xib, xjb, inv_ni, inv_nj, diag, rowsum);
    dim3 grid(NR / BN, NR / BM);
    gemm_rowsum<<<grid, 256, 0, stream>>>(xib, xjb, inv_ni, inv_nj, rowsum);
    finalize<<<1, 256, 0, stream>>>(rowsum, diag, (float*)d_out);
}